// Round 7
// baseline (659.279 us; speedup 1.0000x reference)
//
#include <hip/hip_runtime.h>
#include <math.h>

#define B_   8
#define C_   256
#define N_   4096
#define CQK_ 64
#define JS_  8

// Qt is pre-scaled by sqrt(log2(e)) so q.k logits are in log2 domain: exp -> v_exp_f32.
#define SCQ 1.20110674f
#define THR2 11.54f            // defer-max threshold (8 nats in log2 units)

typedef __attribute__((ext_vector_type(8))) short short8v;   // 8 x bf16 (4 VGPRs)
typedef __attribute__((ext_vector_type(4))) short short4v;   // 4 x bf16 (8B)
typedef __attribute__((ext_vector_type(4))) float f32x4;

__device__ __forceinline__ unsigned short f2bf(float f) {
    unsigned u = __float_as_uint(f);
    u += 0x7fffu + ((u >> 16) & 1u);
    return (unsigned short)(u >> 16);
}
__device__ __forceinline__ float bf2f(unsigned short h) {
    return __uint_as_float((unsigned)h << 16);
}

// ------------------------------------------------ weights fp32 -> bf16 (row-major, packed)
__global__ __launch_bounds__(256) void wcvt_kernel(const float* __restrict__ wqk,
                                                   const float* __restrict__ wv,
                                                   const float* __restrict__ wt,
                                                   unsigned short* __restrict__ wh) {
    int i = (blockIdx.x * 256 + threadIdx.x) * 4;   // 144*256*4 = 147456 total
    const float* src; int off;
    if (i < 16384)      { src = wqk; off = i; }
    else if (i < 81920) { src = wv;  off = i - 16384; }
    else                { src = wt;  off = i - 81920; }
    float4 v = *(const float4*)(src + off);
    short4v o;
    o[0] = (short)f2bf(v.x); o[1] = (short)f2bf(v.y);
    o[2] = (short)f2bf(v.z); o[3] = (short)f2bf(v.w);
    *(short4v*)(wh + i) = o;
}

// --------------------------- xs = x + xyz (fp32 [b][c][n]) AND xst bf16 transposed [b][n][c]
__global__ __launch_bounds__(256) void addt_kernel(const float* __restrict__ x,
                                                   const float* __restrict__ xyz,
                                                   float* __restrict__ xs,
                                                   unsigned short* __restrict__ xst) {
    __shared__ float st[64][65];
    const int tid = threadIdx.x;
    const int n0 = blockIdx.x * 64, c0 = blockIdx.y * 64, b = blockIdx.z;
    const size_t base = ((size_t)b * C_ + c0) * N_ + n0;
#pragma unroll
    for (int r = 0; r < 4; ++r) {
        int c = r * 16 + (tid >> 4);
        int nc = (tid & 15) * 4;
        size_t off = base + (size_t)c * N_ + nc;
        float4 xv = *(const float4*)(x + off);
        float4 yv = *(const float4*)(xyz + off);
        float4 s = make_float4(xv.x + yv.x, xv.y + yv.y, xv.z + yv.z, xv.w + yv.w);
        *(float4*)(xs + off) = s;
        st[c][nc] = s.x; st[c][nc + 1] = s.y; st[c][nc + 2] = s.z; st[c][nc + 3] = s.w;
    }
    __syncthreads();
    int n = tid >> 2, cc = (tid & 3) * 16;
    short8v p0, p1;
#pragma unroll
    for (int j = 0; j < 8; ++j) {
        p0[j] = (short)f2bf(st[cc + j][n]);
        p1[j] = (short)f2bf(st[cc + 8 + j][n]);
    }
    size_t ob = ((size_t)b * N_ + n0 + n) * 256 + c0 + cc;
    *(short8v*)(xst + ob) = p0;
    *(short8v*)(xst + ob + 8) = p1;
}

// --------------------- Q-conv (MFMA): out Qt[b][n][64] bf16, pre-scaled by SCQ (log2 domain)
__global__ __launch_bounds__(256, 4) void convq_kernel(const unsigned short* __restrict__ xst,
                                                       const unsigned short* __restrict__ wh,
                                                       const float* __restrict__ bias,
                                                       unsigned short* __restrict__ Qt) {
    const int tid = threadIdx.x, wave = tid >> 6, lane = tid & 63, q = lane & 15, g = lane >> 4;
    const int n0 = blockIdx.x * 64, b = blockIdx.y;
    const unsigned short* xb = xst + (size_t)b * N_ * 256;
    f32x4 acc[4];
#pragma unroll
    for (int j = 0; j < 4; ++j) acc[j] = (f32x4){0.f, 0.f, 0.f, 0.f};
    for (int ks = 0; ks < 8; ++ks) {
        short8v aw = *(const short8v*)(wh + (size_t)(wave * 16 + q) * 256 + ks * 32 + 8 * g);
#pragma unroll
        for (int j = 0; j < 4; ++j) {
            short8v bx = *(const short8v*)(xb + (size_t)(n0 + j * 16 + q) * 256 + ks * 32 + 8 * g);
            acc[j] = __builtin_amdgcn_mfma_f32_16x16x32_bf16(aw, bx, acc[j], 0, 0, 0);
        }
    }
#pragma unroll
    for (int j = 0; j < 4; ++j) {
        short4v pk;
#pragma unroll
        for (int r = 0; r < 4; ++r)
            pk[r] = (short)f2bf((acc[j][r] + bias[wave * 16 + 4 * g + r]) * SCQ);
        *(short4v*)(Qt + ((size_t)b * N_ + n0 + j * 16 + q) * 64 + wave * 16 + 4 * g) = pk;
    }
}

// --------------------- V-conv (MFMA): out Vh[b][c][n] bf16, PRE-SCALED by rsinv[n]
__global__ __launch_bounds__(512, 2) void convv_kernel(const unsigned short* __restrict__ xst,
                                                       const unsigned short* __restrict__ wh,
                                                       const float* __restrict__ bias,
                                                       const float* __restrict__ rsinv,
                                                       unsigned short* __restrict__ Vh) {
    const int tid = threadIdx.x, wave = tid >> 6, lane = tid & 63, q = lane & 15, g = lane >> 4;
    const int n0 = blockIdx.x * 64, o0 = blockIdx.y * 128, b = blockIdx.z;
    const int oo = o0 + wave * 16;
    const unsigned short* xb = xst + (size_t)b * N_ * 256;
    const float* rsb = rsinv + (size_t)b * N_;
    f32x4 acc[4];
#pragma unroll
    for (int j = 0; j < 4; ++j) acc[j] = (f32x4){0.f, 0.f, 0.f, 0.f};
    for (int ks = 0; ks < 8; ++ks) {
        short8v bw = *(const short8v*)(wh + (size_t)(oo + q) * 256 + ks * 32 + 8 * g);
#pragma unroll
        for (int j = 0; j < 4; ++j) {
            short8v ax = *(const short8v*)(xb + (size_t)(n0 + j * 16 + q) * 256 + ks * 32 + 8 * g);
            acc[j] = __builtin_amdgcn_mfma_f32_16x16x32_bf16(ax, bw, acc[j], 0, 0, 0);
        }
    }
    float bo = bias[oo + q];
#pragma unroll
    for (int j = 0; j < 4; ++j) {
        f32x4 rs4 = *(const f32x4*)(rsb + n0 + j * 16 + 4 * g);   // n = n0+j*16+4g+r
        short4v pk;
#pragma unroll
        for (int r = 0; r < 4; ++r) pk[r] = (short)f2bf((acc[j][r] + bo) * rs4[r]);
        *(short4v*)(Vh + ((size_t)b * C_ + oo + q) * N_ + n0 + j * 16 + 4 * g) = pk;
    }
}

// ------------------ pass A: per-row softmax stats via MFMA, log2 domain, defer-max
__global__ __launch_bounds__(256) void rowstats_mfma(const unsigned short* __restrict__ Qt,
                                                     float* __restrict__ pmax,
                                                     float* __restrict__ psum) {
    const int tid = threadIdx.x;
    const int wave = tid >> 6, lane = tid & 63, q = lane & 15, g = lane >> 4;
    const int bid = blockIdx.x;
    const int b  = bid & 7;
    const int it = (bid >> 3) & 63;
    const int js = bid >> 9;
    const int i0 = it * 64 + wave * 16;
    const unsigned short* Qb = Qt + (size_t)b * N_ * CQK_;

    const unsigned short* bp = Qb + (size_t)(i0 + q) * CQK_ + 8 * g;
    short8v bq0 = *(const short8v*)bp;
    short8v bq1 = *(const short8v*)(bp + 32);

    float m = -1e30f, s = 0.f;
    const int jbeg = js * (N_ / JS_);
    for (int j0 = jbeg; j0 < jbeg + N_ / JS_; j0 += 16) {
        const unsigned short* ap = Qb + (size_t)(j0 + q) * CQK_ + 8 * g;
        short8v a0 = *(const short8v*)ap;
        short8v a1 = *(const short8v*)(ap + 32);
        f32x4 e = {0.f, 0.f, 0.f, 0.f};
        e = __builtin_amdgcn_mfma_f32_16x16x32_bf16(a0, bq0, e, 0, 0, 0);
        e = __builtin_amdgcn_mfma_f32_16x16x32_bf16(a1, bq1, e, 0, 0, 0);
        float pm = fmaxf(fmaxf(e[0], e[1]), fmaxf(e[2], e[3]));
        if (!__all(pm <= m + THR2)) {   // defer-max: rescale only on violation (rare)
            float mn = fmaxf(m, pm);
            s *= exp2f(m - mn);
            m = mn;
        }
        s += (exp2f(e[0] - m) + exp2f(e[1] - m)) + (exp2f(e[2] - m) + exp2f(e[3] - m));
    }
#pragma unroll
    for (int off = 16; off <= 32; off <<= 1) {
        float mo = __shfl_xor(m, off);
        float so = __shfl_xor(s, off);
        float mn = fmaxf(m, mo);
        s = s * exp2f(m - mn) + so * exp2f(mo - mn);
        m = mn;
    }
    if (lane < 16) {
        size_t o = ((size_t)js * B_ + b) * N_ + i0 + q;
        pmax[o] = m;
        psum[o] = s;
    }
}

__global__ __launch_bounds__(256) void rowmerge_kernel(const float* __restrict__ pmax,
                                                       const float* __restrict__ psum,
                                                       float* __restrict__ rm,
                                                       float* __restrict__ rsinv) {
    size_t i = (size_t)blockIdx.x * 256 + threadIdx.x;
    float m = -1e30f;
#pragma unroll
    for (int js = 0; js < JS_; ++js) m = fmaxf(m, pmax[(size_t)js * B_ * N_ + i]);
    float s = 0.f;
#pragma unroll
    for (int js = 0; js < JS_; ++js)
        s += psum[(size_t)js * B_ * N_ + i] * exp2f(pmax[(size_t)js * B_ * N_ + i] - m);
    rm[i] = m;
    rsinv[i] = 1.f / s;
}

// --------- pass B: 4-wave blocks, m-tile 32, full n-range. Wave w = energy n-block w,
//           PV c-slice w*64..w*64+63. V pre-scaled by rsinv. Fused diff epilogue -> dh.
__global__ __launch_bounds__(256, 4) void pv_mfma(const unsigned short* __restrict__ Qt,
                                                  const unsigned short* __restrict__ Vh,
                                                  const float* __restrict__ rm,
                                                  const float* __restrict__ rsinv,
                                                  unsigned short* __restrict__ dh) {
    __shared__ unsigned short saT[2][2048];      // [buf][m 32][n 64] bf16, 128B pitch, swizzled
    __shared__ float scs[4][2][16];
    __shared__ float scsf[32];
    const int tid = threadIdx.x;
    const int wave = tid >> 6, lane = tid & 63, q = lane & 15, g = lane >> 4;
    const int bid = blockIdx.x;
    const int b  = bid & 7;                // XCD-pinned: one batch per XCD
    const int m0 = (bid >> 3) << 5;        // m-tile of 32
    const unsigned short* Qb = Qt + (size_t)b * N_ * CQK_;
    const unsigned short* Vb = Vh + (size_t)b * C_ * N_;
    const float* rmb = rm + (size_t)b * N_;
    const float* rsb = rsinv + (size_t)b * N_;
    unsigned short* dhb = dh + (size_t)b * N_ * 256;

    short8v bqm[2][2];                     // energy B-frags: Q columns m (2 m16-blocks)
#pragma unroll
    for (int mi = 0; mi < 2; ++mi) {
        const unsigned short* p = Qb + (size_t)(m0 + mi * 16 + q) * CQK_ + 8 * g;
        bqm[mi][0] = *(const short8v*)p;
        bqm[mi][1] = *(const short8v*)(p + 32);
    }

    // tile-0 A-frags (this wave's n16-block) + stats
    const unsigned short* ap0 = Qb + (size_t)(wave * 16 + q) * CQK_ + 8 * g;
    short8v an0 = *(const short8v*)ap0;
    short8v an1 = *(const short8v*)(ap0 + 32);
    f32x4 rmc = *(const f32x4*)(rmb + wave * 16 + 4 * g);
    f32x4 rsc = *(const f32x4*)(rsb + wave * 16 + 4 * g);

    f32x4 acc[4][2];                       // [cblk][mb]: c = wave*64+cblk*16+4g+r, m = m0+mb*16+q
#pragma unroll
    for (int cb = 0; cb < 4; ++cb)
#pragma unroll
        for (int mb = 0; mb < 2; ++mb) acc[cb][mb] = (f32x4){0.f, 0.f, 0.f, 0.f};
    float csum0 = 0.f, csum1 = 0.f;

    // energy for tile te: P' = exp2(e - rm), csum += P'*rs (colsum weights), write saT[te&1]
    auto energy = [&](int te, short8v ea0, short8v ea1, f32x4 rm4, f32x4 rs4) {
        char* base = (char*)saT + (te & 1) * 4096;
#pragma unroll
        for (int mi = 0; mi < 2; ++mi) {
            f32x4 e = {0.f, 0.f, 0.f, 0.f};
            e = __builtin_amdgcn_mfma_f32_16x16x32_bf16(ea0, bqm[mi][0], e, 0, 0, 0);
            e = __builtin_amdgcn_mfma_f32_16x16x32_bf16(ea1, bqm[mi][1], e, 0, 0, 0);
            const int mcol = mi * 16 + q;
            float p0 = exp2f(e[0] - rm4[0]);
            float p1 = exp2f(e[1] - rm4[1]);
            float p2 = exp2f(e[2] - rm4[2]);
            float p3 = exp2f(e[3] - rm4[3]);
            float cs = p0 * rs4[0] + p1 * rs4[1] + p2 * rs4[2] + p3 * rs4[3];
            if (mi == 0) csum0 += cs; else csum1 += cs;
            unsigned pk0, pk1;
            asm("v_cvt_pk_bf16_f32 %0, %1, %2" : "=v"(pk0) : "v"(p0), "v"(p1));
            asm("v_cvt_pk_bf16_f32 %0, %1, %2" : "=v"(pk1) : "v"(p2), "v"(p3));
            uint2 w; w.x = pk0; w.y = pk1;
            const int byte = mcol * 128 + ((2 * (wave * 16 + 4 * g)) ^ ((mcol & 7) << 4));
            *(uint2*)(base + byte) = w;
        }
    };

    const int T = N_ / 64;   // 64 tiles
    energy(0, an0, an1, rmc, rsc);
    {
        const unsigned short* p = Qb + (size_t)(64 + wave * 16 + q) * CQK_ + 8 * g;
        an0 = *(const short8v*)p;
        an1 = *(const short8v*)(p + 32);
        rmc = *(const f32x4*)(rmb + 64 + wave * 16 + 4 * g);
        rsc = *(const f32x4*)(rsb + 64 + wave * 16 + 4 * g);
    }
    __syncthreads();   // saT[0] visible

    for (int t = 0; t < T - 1; ++t) {
        const int n0g = t * 64;
        char* rbase = (char*)saT + (t & 1) * 4096;
        // V' A-frags for PV(t): 8 x 16B from L2 (c = wave*64+cb*16+q, k = n)
        short8v vf[2][4];
#pragma unroll
        for (int ch = 0; ch < 2; ++ch)
#pragma unroll
            for (int cb = 0; cb < 4; ++cb)
                vf[ch][cb] = *(const short8v*)(Vb + (size_t)(wave * 64 + cb * 16 + q) * N_
                                               + n0g + ch * 32 + 8 * g);
        // B-frags ch=0 (buffer t&1, written before last barrier)
        short8v bf0[2];
#pragma unroll
        for (int mb = 0; mb < 2; ++mb) {
            int row = mb * 16 + q;
            int byte = row * 128 + ((16 * g) ^ ((row & 7) << 4));
            bf0[mb] = *(const short8v*)(rbase + byte);
        }
        // energy(t+1) — independent of PV(t)
        energy(t + 1, an0, an1, rmc, rsc);
        // prefetch A-frags + stats for tile t+2
        const int t2 = (t + 2 < T) ? t + 2 : 0;
        const unsigned short* pn = Qb + (size_t)(t2 * 64 + wave * 16 + q) * CQK_ + 8 * g;
        short8v an0n = *(const short8v*)pn;
        short8v an1n = *(const short8v*)(pn + 32);
        f32x4 rmn = *(const f32x4*)(rmb + t2 * 64 + wave * 16 + 4 * g);
        f32x4 rsn = *(const f32x4*)(rsb + t2 * 64 + wave * 16 + 4 * g);
        // B-frags ch=1
        short8v bf1[2];
#pragma unroll
        for (int mb = 0; mb < 2; ++mb) {
            int row = mb * 16 + q;
            int byte = row * 128 + ((16 * (g + 4)) ^ ((row & 7) << 4));
            bf1[mb] = *(const short8v*)(rbase + byte);
        }
        // PV(t): 16 MFMAs
        __builtin_amdgcn_s_setprio(1);
#pragma unroll
        for (int cb = 0; cb < 4; ++cb)
#pragma unroll
            for (int mb = 0; mb < 2; ++mb)
                acc[cb][mb] = __builtin_amdgcn_mfma_f32_16x16x32_bf16(vf[0][cb], bf0[mb],
                                                                      acc[cb][mb], 0, 0, 0);
#pragma unroll
        for (int cb = 0; cb < 4; ++cb)
#pragma unroll
            for (int mb = 0; mb < 2; ++mb)
                acc[cb][mb] = __builtin_amdgcn_mfma_f32_16x16x32_bf16(vf[1][cb], bf1[mb],
                                                                      acc[cb][mb], 0, 0, 0);
        __builtin_amdgcn_s_setprio(0);
        an0 = an0n; an1 = an1n; rmc = rmn; rsc = rsn;
        __syncthreads();   // saT[(t+1)&1] visible; protects buffer t&1
    }
    // epilogue tile T-1: PV only
    {
        const int n0g = (T - 1) * 64;
        char* rbase = (char*)saT + ((T - 1) & 1) * 4096;
#pragma unroll
        for (int ch = 0; ch < 2; ++ch) {
            short8v bfrag[2];
#pragma unroll
            for (int mb = 0; mb < 2; ++mb) {
                int row = mb * 16 + q;
                int byte = row * 128 + ((16 * (g + 4 * ch)) ^ ((row & 7) << 4));
                bfrag[mb] = *(const short8v*)(rbase + byte);
            }
#pragma unroll
            for (int cb = 0; cb < 4; ++cb) {
                short8v vf = *(const short8v*)(Vb + (size_t)(wave * 64 + cb * 16 + q) * N_
                                               + n0g + ch * 32 + 8 * g);
#pragma unroll
                for (int mb = 0; mb < 2; ++mb)
                    acc[cb][mb] = __builtin_amdgcn_mfma_f32_16x16x32_bf16(vf, bfrag[mb],
                                                                          acc[cb][mb], 0, 0, 0);
            }
        }
    }

    // ---- column sums (full, NSPLIT=1): reduce over g within wave, then over 4 waves
    csum0 += __shfl_xor(csum0, 16); csum0 += __shfl_xor(csum0, 32);
    csum1 += __shfl_xor(csum1, 16); csum1 += __shfl_xor(csum1, 32);
    if (lane < 16) { scs[wave][0][q] = csum0; scs[wave][1][q] = csum1; }
    __syncthreads();
    if (tid < 32) {
        int mb = tid >> 4, qq = tid & 15;
        float cs = 0.f;
#pragma unroll
        for (int w = 0; w < 4; ++w) cs += scs[w][mb][qq];
        scsf[tid] = cs;
    }
    __syncthreads();
    // ---- fused diff epilogue: dh[m][c] = bf16( xst[m][c] - acc/(1e-9+cs[m]) ), in place
#pragma unroll
    for (int mb = 0; mb < 2; ++mb) {
        const int m = m0 + mb * 16 + q;
        const float inv = 1.f / (1e-9f + scsf[mb * 16 + q]);
#pragma unroll
        for (int cb = 0; cb < 4; ++cb) {
            const int c = wave * 64 + cb * 16 + 4 * g;
            unsigned short* dp = dhb + (size_t)m * 256 + c;
            short4v xv = *(const short4v*)dp;
            short4v pk;
#pragma unroll
            for (int r = 0; r < 4; ++r)
                pk[r] = (short)f2bf(bf2f((unsigned short)xv[r]) - acc[cb][mb][r] * inv);
            *(short4v*)dp = pk;
        }
    }
}

// ------- t-conv + finalize (MFMA), 128-wide c-tile: out = xs + leaky(bn(t))
__global__ __launch_bounds__(512, 2) void convt_kernel(const unsigned short* __restrict__ dh,
                                                       const unsigned short* __restrict__ wh,
                                                       const float* __restrict__ bt,
                                                       const float* __restrict__ xs,
                                                       float* __restrict__ out,
                                                       const float* __restrict__ gam,
                                                       const float* __restrict__ bet,
                                                       const float* __restrict__ mu,
                                                       const float* __restrict__ var) {
    const int tid = threadIdx.x, wave = tid >> 6, lane = tid & 63, q = lane & 15, g = lane >> 4;
    const int m0 = blockIdx.x * 64, c0 = blockIdx.y * 128, b = blockIdx.z;
    const int cc = c0 + wave * 16;
    const unsigned short* db = dh + (size_t)b * N_ * 256;
    f32x4 acc[4];
#pragma unroll
    for (int j = 0; j < 4; ++j) acc[j] = (f32x4){0.f, 0.f, 0.f, 0.f};
    for (int ks = 0; ks < 8; ++ks) {
        short8v bw = *(const short8v*)(wh + (size_t)(cc + q) * 256 + ks * 32 + 8 * g);
#pragma unroll
        for (int j = 0; j < 4; ++j) {
            short8v ad = *(const short8v*)(db + (size_t)(m0 + j * 16 + q) * 256 + ks * 32 + 8 * g);
            acc[j] = __builtin_amdgcn_mfma_f32_16x16x32_bf16(ad, bw, acc[j], 0, 0, 0);
        }
    }
    const int c = cc + q;
    const float sc = rsqrtf(var[c] + 1e-5f) * gam[c];
    const float sh = bet[c] - mu[c] * sc;
    const float bb = bt[c];
#pragma unroll
    for (int j = 0; j < 4; ++j) {
        size_t off = ((size_t)b * C_ + c) * N_ + m0 + j * 16 + 4 * g;
        float4 xv = *(const float4*)(xs + off);
        float4 o;
        float tn;
        tn = (acc[j][0] + bb) * sc + sh; o.x = xv.x + (tn >= 0.f ? tn : 0.2f * tn);
        tn = (acc[j][1] + bb) * sc + sh; o.y = xv.y + (tn >= 0.f ? tn : 0.2f * tn);
        tn = (acc[j][2] + bb) * sc + sh; o.z = xv.z + (tn >= 0.f ? tn : 0.2f * tn);
        tn = (acc[j][3] + bb) * sc + sh; o.w = xv.w + (tn >= 0.f ? tn : 0.2f * tn);
        *(float4*)(out + off) = o;
    }
}

// ----------------------------------------------------------------------------------------
extern "C" void kernel_launch(void* const* d_in, const int* in_sizes, int n_in,
                              void* d_out, int out_size, void* d_ws, size_t ws_size,
                              hipStream_t stream) {
    (void)in_sizes; (void)n_in; (void)out_size; (void)ws_size;
    const float* x   = (const float*)d_in[0];
    const float* xyz = (const float*)d_in[1];
    const float* wqk = (const float*)d_in[2];
    const float* bqk = (const float*)d_in[3];
    const float* wv  = (const float*)d_in[4];
    const float* bv  = (const float*)d_in[5];
    const float* wt  = (const float*)d_in[6];
    const float* bt  = (const float*)d_in[7];
    const float* gam = (const float*)d_in[8];
    const float* bet = (const float*)d_in[9];
    const float* mu  = (const float*)d_in[10];
    const float* var = (const float*)d_in[11];
    float* out = (float*)d_out;

    const size_t M8 = (size_t)B_ * C_ * N_;   // 8M elements
    float* ws = (float*)d_ws;
    size_t off = 0;
    float* xs = ws + off;                              off += M8;       // fp32 [b][c][n] 32MB
    unsigned short* xst = (unsigned short*)(ws + off); off += M8 / 2;   // bf16 [b][n][c] 16MB
    unsigned short* Qt  = (unsigned short*)(ws + off); off += M8 / 8;   // bf16 [b][n][64] 4MB
    unsigned short* Vh  = (unsigned short*)(ws + off); off += M8 / 2;   // bf16 [b][c][n] 16MB
    unsigned short* wh  = (unsigned short*)(ws + off); off += 81920;    // bf16 weights
    float* pmax = ws + off; off += (size_t)JS_ * B_ * N_;
    float* psum = ws + off; off += (size_t)JS_ * B_ * N_;
    float* rmb  = ws + off; off += (size_t)B_ * N_;
    float* rsb  = ws + off; off += (size_t)B_ * N_;
    unsigned short* dhb = xst;   // pv fuses diff, updating xst in place -> dh

    wcvt_kernel<<<dim3(144), dim3(256), 0, stream>>>(wqk, wv, wt, wh);
    addt_kernel<<<dim3(N_ / 64, C_ / 64, B_), dim3(256), 0, stream>>>(x, xyz, xs, xst);
    convq_kernel<<<dim3(N_ / 64, B_), dim3(256), 0, stream>>>(xst, wh, bqk, Qt);
    rowstats_mfma<<<dim3(B_ * (N_ / 64) * JS_), dim3(256), 0, stream>>>(Qt, pmax, psum);
    rowmerge_kernel<<<dim3(B_ * N_ / 256), dim3(256), 0, stream>>>(pmax, psum, rmb, rsb);
    convv_kernel<<<dim3(N_ / 64, C_ / 128, B_), dim3(512), 0, stream>>>(
        xst, wh + 16384, bv, rsb, Vh);
    pv_mfma<<<dim3(B_ * (N_ / 32)), dim3(256), 0, stream>>>(Qt, Vh, rmb, rsb, dhb);
    convt_kernel<<<dim3(N_ / 64, C_ / 128, B_), dim3(512), 0, stream>>>(
        dhb, wh + 81920, bt, xs, out, gam, bet, mu, var);
}

// Round 8
// 568.035 us; speedup vs baseline: 1.1606x; 1.1606x over previous
//
#include <hip/hip_runtime.h>
#include <math.h>

#define B_   8
#define C_   256
#define N_   4096
#define CQK_ 64
#define JS_  8
#define NSPLIT 2
#define NRANGE (N_ / NSPLIT)   // 2048

// Qt is pre-scaled by sqrt(log2(e)) so q.k logits are in log2 domain: exp -> v_exp_f32.
#define SCQ 1.20110674f
#define THR2 11.54f            // defer-max threshold (8 nats in log2 units)

typedef __attribute__((ext_vector_type(8))) short short8v;    // 8 x bf16 (4 VGPRs)
typedef __attribute__((ext_vector_type(4))) short short4v;    // 4 x bf16 (8B)
typedef __attribute__((ext_vector_type(4))) float f32x4;
typedef __attribute__((ext_vector_type(16))) float f32x16;
typedef __attribute__((ext_vector_type(4))) unsigned int uint4v;

__device__ __forceinline__ unsigned short f2bf(float f) {
    unsigned u = __float_as_uint(f);
    u += 0x7fffu + ((u >> 16) & 1u);
    return (unsigned short)(u >> 16);
}
__device__ __forceinline__ float bf2f(unsigned short h) {
    return __uint_as_float((unsigned)h << 16);
}

// ------------------------------------------------ weights fp32 -> bf16 (row-major, packed)
__global__ __launch_bounds__(256) void wcvt_kernel(const float* __restrict__ wqk,
                                                   const float* __restrict__ wv,
                                                   const float* __restrict__ wt,
                                                   unsigned short* __restrict__ wh) {
    int i = (blockIdx.x * 256 + threadIdx.x) * 4;   // 144*256*4 = 147456 total
    const float* src; int off;
    if (i < 16384)      { src = wqk; off = i; }
    else if (i < 81920) { src = wv;  off = i - 16384; }
    else                { src = wt;  off = i - 81920; }
    float4 v = *(const float4*)(src + off);
    short4v o;
    o[0] = (short)f2bf(v.x); o[1] = (short)f2bf(v.y);
    o[2] = (short)f2bf(v.z); o[3] = (short)f2bf(v.w);
    *(short4v*)(wh + i) = o;
}

// --------------------------- xs = x + xyz (fp32 [b][c][n]) AND xst bf16 transposed [b][n][c]
__global__ __launch_bounds__(256) void addt_kernel(const float* __restrict__ x,
                                                   const float* __restrict__ xyz,
                                                   float* __restrict__ xs,
                                                   unsigned short* __restrict__ xst) {
    __shared__ float st[64][65];
    const int tid = threadIdx.x;
    const int n0 = blockIdx.x * 64, c0 = blockIdx.y * 64, b = blockIdx.z;
    const size_t base = ((size_t)b * C_ + c0) * N_ + n0;
#pragma unroll
    for (int r = 0; r < 4; ++r) {
        int c = r * 16 + (tid >> 4);
        int nc = (tid & 15) * 4;
        size_t off = base + (size_t)c * N_ + nc;
        float4 xv = *(const float4*)(x + off);
        float4 yv = *(const float4*)(xyz + off);
        float4 s = make_float4(xv.x + yv.x, xv.y + yv.y, xv.z + yv.z, xv.w + yv.w);
        *(float4*)(xs + off) = s;
        st[c][nc] = s.x; st[c][nc + 1] = s.y; st[c][nc + 2] = s.z; st[c][nc + 3] = s.w;
    }
    __syncthreads();
    int n = tid >> 2, cc = (tid & 3) * 16;
    short8v p0, p1;
#pragma unroll
    for (int j = 0; j < 8; ++j) {
        p0[j] = (short)f2bf(st[cc + j][n]);
        p1[j] = (short)f2bf(st[cc + 8 + j][n]);
    }
    size_t ob = ((size_t)b * N_ + n0 + n) * 256 + c0 + cc;
    *(short8v*)(xst + ob) = p0;
    *(short8v*)(xst + ob + 8) = p1;
}

// --------------------- Q-conv (MFMA): out Qt[b][n][64] bf16, pre-scaled by SCQ (log2 domain)
__global__ __launch_bounds__(256, 4) void convq_kernel(const unsigned short* __restrict__ xst,
                                                       const unsigned short* __restrict__ wh,
                                                       const float* __restrict__ bias,
                                                       unsigned short* __restrict__ Qt) {
    const int tid = threadIdx.x, wave = tid >> 6, lane = tid & 63, q = lane & 15, g = lane >> 4;
    const int n0 = blockIdx.x * 64, b = blockIdx.y;
    const unsigned short* xb = xst + (size_t)b * N_ * 256;
    f32x4 acc[4];
#pragma unroll
    for (int j = 0; j < 4; ++j) acc[j] = (f32x4){0.f, 0.f, 0.f, 0.f};
    for (int ks = 0; ks < 8; ++ks) {
        short8v aw = *(const short8v*)(wh + (size_t)(wave * 16 + q) * 256 + ks * 32 + 8 * g);
#pragma unroll
        for (int j = 0; j < 4; ++j) {
            short8v bx = *(const short8v*)(xb + (size_t)(n0 + j * 16 + q) * 256 + ks * 32 + 8 * g);
            acc[j] = __builtin_amdgcn_mfma_f32_16x16x32_bf16(aw, bx, acc[j], 0, 0, 0);
        }
    }
#pragma unroll
    for (int j = 0; j < 4; ++j) {
        short4v pk;
#pragma unroll
        for (int r = 0; r < 4; ++r)
            pk[r] = (short)f2bf((acc[j][r] + bias[wave * 16 + 4 * g + r]) * SCQ);
        *(short4v*)(Qt + ((size_t)b * N_ + n0 + j * 16 + q) * 64 + wave * 16 + 4 * g) = pk;
    }
}

// --------------------- V-conv (MFMA): out Vh[b][c][n] bf16, PRE-SCALED by rsinv[n]
__global__ __launch_bounds__(512, 2) void convv_kernel(const unsigned short* __restrict__ xst,
                                                       const unsigned short* __restrict__ wh,
                                                       const float* __restrict__ bias,
                                                       const float* __restrict__ rsinv,
                                                       unsigned short* __restrict__ Vh) {
    const int tid = threadIdx.x, wave = tid >> 6, lane = tid & 63, q = lane & 15, g = lane >> 4;
    const int n0 = blockIdx.x * 64, o0 = blockIdx.y * 128, b = blockIdx.z;
    const int oo = o0 + wave * 16;
    const unsigned short* xb = xst + (size_t)b * N_ * 256;
    const float* rsb = rsinv + (size_t)b * N_;
    f32x4 acc[4];
#pragma unroll
    for (int j = 0; j < 4; ++j) acc[j] = (f32x4){0.f, 0.f, 0.f, 0.f};
    for (int ks = 0; ks < 8; ++ks) {
        short8v bw = *(const short8v*)(wh + (size_t)(oo + q) * 256 + ks * 32 + 8 * g);
#pragma unroll
        for (int j = 0; j < 4; ++j) {
            short8v ax = *(const short8v*)(xb + (size_t)(n0 + j * 16 + q) * 256 + ks * 32 + 8 * g);
            acc[j] = __builtin_amdgcn_mfma_f32_16x16x32_bf16(ax, bw, acc[j], 0, 0, 0);
        }
    }
    float bo = bias[oo + q];
#pragma unroll
    for (int j = 0; j < 4; ++j) {
        f32x4 rs4 = *(const f32x4*)(rsb + n0 + j * 16 + 4 * g);   // n = n0+j*16+4g+r
        short4v pk;
#pragma unroll
        for (int r = 0; r < 4; ++r) pk[r] = (short)f2bf((acc[j][r] + bo) * rs4[r]);
        *(short4v*)(Vh + ((size_t)b * C_ + oo + q) * N_ + n0 + j * 16 + 4 * g) = pk;
    }
}

// ------------------ pass A: per-row softmax stats via MFMA, log2 domain, defer-max
__global__ __launch_bounds__(256) void rowstats_mfma(const unsigned short* __restrict__ Qt,
                                                     float* __restrict__ pmax,
                                                     float* __restrict__ psum) {
    const int tid = threadIdx.x;
    const int wave = tid >> 6, lane = tid & 63, q = lane & 15, g = lane >> 4;
    const int bid = blockIdx.x;
    const int b  = bid & 7;
    const int it = (bid >> 3) & 63;
    const int js = bid >> 9;
    const int i0 = it * 64 + wave * 16;
    const unsigned short* Qb = Qt + (size_t)b * N_ * CQK_;

    const unsigned short* bp = Qb + (size_t)(i0 + q) * CQK_ + 8 * g;
    short8v bq0 = *(const short8v*)bp;
    short8v bq1 = *(const short8v*)(bp + 32);

    float m = -1e30f, s = 0.f;
    const int jbeg = js * (N_ / JS_);
    for (int j0 = jbeg; j0 < jbeg + N_ / JS_; j0 += 16) {
        const unsigned short* ap = Qb + (size_t)(j0 + q) * CQK_ + 8 * g;
        short8v a0 = *(const short8v*)ap;
        short8v a1 = *(const short8v*)(ap + 32);
        f32x4 e = {0.f, 0.f, 0.f, 0.f};
        e = __builtin_amdgcn_mfma_f32_16x16x32_bf16(a0, bq0, e, 0, 0, 0);
        e = __builtin_amdgcn_mfma_f32_16x16x32_bf16(a1, bq1, e, 0, 0, 0);
        float pm = fmaxf(fmaxf(e[0], e[1]), fmaxf(e[2], e[3]));
        if (!__all(pm <= m + THR2)) {   // defer-max: rescale only on violation (rare)
            float mn = fmaxf(m, pm);
            s *= exp2f(m - mn);
            m = mn;
        }
        s += (exp2f(e[0] - m) + exp2f(e[1] - m)) + (exp2f(e[2] - m) + exp2f(e[3] - m));
    }
#pragma unroll
    for (int off = 16; off <= 32; off <<= 1) {
        float mo = __shfl_xor(m, off);
        float so = __shfl_xor(s, off);
        float mn = fmaxf(m, mo);
        s = s * exp2f(m - mn) + so * exp2f(mo - mn);
        m = mn;
    }
    if (lane < 16) {
        size_t o = ((size_t)js * B_ + b) * N_ + i0 + q;
        pmax[o] = m;
        psum[o] = s;
    }
}

// rowmerge: stores NEGATED rm (pv uses it directly as the MFMA C-init) + rsinv
__global__ __launch_bounds__(256) void rowmerge_kernel(const float* __restrict__ pmax,
                                                       const float* __restrict__ psum,
                                                       float* __restrict__ rmneg,
                                                       float* __restrict__ rsinv) {
    size_t i = (size_t)blockIdx.x * 256 + threadIdx.x;
    float m = -1e30f;
#pragma unroll
    for (int js = 0; js < JS_; ++js) m = fmaxf(m, pmax[(size_t)js * B_ * N_ + i]);
    float s = 0.f;
#pragma unroll
    for (int js = 0; js < JS_; ++js)
        s += psum[(size_t)js * B_ * N_ + i] * exp2f(pmax[(size_t)js * B_ * N_ + i] - m);
    rmneg[i] = -m;
    rsinv[i] = 1.f / s;
}

// --------- pass B: barrier-free, LDS-free. One wave = m-tile 32 x full c=256, n-split 2.
// energy 32x32x16 (C-init = -rm) -> exp2 -> cvt_pk -> permlane32_swap -> PV 32x32x16.
// P column m stays lane-local (col=lane&31); only a lane-half swap redistributes rows.
__global__ __launch_bounds__(256, 2) void pv_mfma32(const unsigned short* __restrict__ Qt,
                                                    const unsigned short* __restrict__ Vh,
                                                    const float* __restrict__ rmneg,
                                                    const float* __restrict__ rsinv,
                                                    unsigned short* __restrict__ pxr,
                                                    float* __restrict__ pcs) {
    const int tid = threadIdx.x;
    const int wave = tid >> 6, lane = tid & 63, l31 = lane & 31, hi = lane >> 5;
    const int bid = blockIdx.x;
    const int b  = bid & 7;                 // XCD-pinned: one batch per XCD
    const int mc = (bid >> 3) & 31;
    const int ns = bid >> 8;
    const int m0 = mc * 128 + wave * 32;    // this wave's m-tile
    const int nbeg = ns * NRANGE;
    const unsigned short* Qb = Qt + (size_t)b * N_ * CQK_;
    const unsigned short* Vb = Vh + (size_t)b * C_ * N_;
    const float* rmb = rmneg + (size_t)b * N_;
    const float* rsb = rsinv + (size_t)b * N_;

    // persistent energy B-frags: col m = m0+l31, k = c (4 k-steps of 16)
    short8v bqm[4];
#pragma unroll
    for (int ks = 0; ks < 4; ++ks)
        bqm[ks] = *(const short8v*)(Qb + (size_t)(m0 + l31) * CQK_ + ks * 16 + 8 * hi);

    f32x16 acc[8];
#pragma unroll
    for (int cb = 0; cb < 8; ++cb)
#pragma unroll
        for (int r = 0; r < 16; ++r) acc[cb][r] = 0.f;
    f32x4 csum4 = {0.f, 0.f, 0.f, 0.f};

    // iter-0 A-frags (rows n = nbeg+l31) + negated rm (reg r+4s -> n = 8s+4hi+r)
    short8v an[4];
    f32x4 rmn[4];
#pragma unroll
    for (int ks = 0; ks < 4; ++ks)
        an[ks] = *(const short8v*)(Qb + (size_t)(nbeg + l31) * CQK_ + ks * 16 + 8 * hi);
#pragma unroll
    for (int s = 0; s < 4; ++s)
        rmn[s] = *(const f32x4*)(rmb + nbeg + 8 * s + 4 * hi);

#pragma unroll 1
    for (int it = 0; it < NRANGE / 32; ++it) {
        const int n0 = nbeg + it * 32;
        // rs for csum (L2-hot, issued early)
        f32x4 rs[4];
#pragma unroll
        for (int s = 0; s < 4; ++s)
            rs[s] = *(const f32x4*)(rsb + n0 + 8 * s + 4 * hi);
        // energy: C-init = -rm (free subtraction), 4 chained k-steps
        f32x16 e;
#pragma unroll
        for (int s = 0; s < 4; ++s) {
            e[4 * s + 0] = rmn[s][0]; e[4 * s + 1] = rmn[s][1];
            e[4 * s + 2] = rmn[s][2]; e[4 * s + 3] = rmn[s][3];
        }
#pragma unroll
        for (int ks = 0; ks < 4; ++ks)
            e = __builtin_amdgcn_mfma_f32_32x32x16_bf16(an[ks], bqm[ks], e, 0, 0, 0);
        // prefetch next-iter A-frags + rm (hides L2 latency under exp/PV)
        const int n1 = (it + 1 < NRANGE / 32) ? n0 + 32 : nbeg;
#pragma unroll
        for (int ks = 0; ks < 4; ++ks)
            an[ks] = *(const short8v*)(Qb + (size_t)(n1 + l31) * CQK_ + ks * 16 + 8 * hi);
#pragma unroll
        for (int s = 0; s < 4; ++s)
            rmn[s] = *(const f32x4*)(rmb + n1 + 8 * s + 4 * hi);
        // exp2 + csum + pack to bf16 dword pairs
        unsigned dw[8];
#pragma unroll
        for (int s = 0; s < 4; ++s) {
            float p0 = exp2f(e[4 * s + 0]);
            float p1 = exp2f(e[4 * s + 1]);
            float p2 = exp2f(e[4 * s + 2]);
            float p3 = exp2f(e[4 * s + 3]);
            csum4[s] += (p0 * rs[s][0] + p1 * rs[s][1]) + (p2 * rs[s][2] + p3 * rs[s][3]);
            asm("v_cvt_pk_bf16_f32 %0, %1, %2" : "=v"(dw[2 * s + 0]) : "v"(p0), "v"(p1));
            asm("v_cvt_pk_bf16_f32 %0, %1, %2" : "=v"(dw[2 * s + 1]) : "v"(p2), "v"(p3));
        }
        // lane-half exchange: a' = [a_lo|b_lo], b' = [a_hi|b_hi]  (exact B-frag words)
        asm("v_permlane32_swap_b32 %0, %1" : "+v"(dw[0]), "+v"(dw[2]));
        asm("v_permlane32_swap_b32 %0, %1" : "+v"(dw[1]), "+v"(dw[3]));
        asm("v_permlane32_swap_b32 %0, %1" : "+v"(dw[4]), "+v"(dw[6]));
        asm("v_permlane32_swap_b32 %0, %1" : "+v"(dw[5]), "+v"(dw[7]));
        uint4v t0 = {dw[0], dw[1], dw[2], dw[3]};
        uint4v t1 = {dw[4], dw[5], dw[6], dw[7]};
        short8v pf0 = __builtin_bit_cast(short8v, t0);   // P rows n0..n0+15
        short8v pf1 = __builtin_bit_cast(short8v, t1);   // P rows n0+16..n0+31
        // PV: acc[c][m] += V'[c][n] * P[n][m]  (V' pre-scaled by rsinv)
#pragma unroll
        for (int cb = 0; cb < 8; ++cb) {
            short8v v0 = *(const short8v*)(Vb + (size_t)(cb * 32 + l31) * N_ + n0 + 8 * hi);
            acc[cb] = __builtin_amdgcn_mfma_f32_32x32x16_bf16(v0, pf0, acc[cb], 0, 0, 0);
        }
#pragma unroll
        for (int cb = 0; cb < 8; ++cb) {
            short8v v1 = *(const short8v*)(Vb + (size_t)(cb * 32 + l31) * N_ + n0 + 16 + 8 * hi);
            acc[cb] = __builtin_amdgcn_mfma_f32_32x32x16_bf16(v1, pf1, acc[cb], 0, 0, 0);
        }
    }

    // partial colsum: lanes l and l+32 hold complementary n-halves of column m
    float csum = (csum4[0] + csum4[1]) + (csum4[2] + csum4[3]);
    csum += __shfl_xor(csum, 32);
    if (lane < 32) pcs[((size_t)ns * B_ + b) * N_ + m0 + lane] = csum;
    // partial XR out: bf16 [ns][b][m][c]; c = cb*32 + 8s + 4hi + r
    unsigned short* pb = pxr + ((size_t)ns * B_ + b) * N_ * 256;
    const int m = m0 + l31;
#pragma unroll
    for (int cb = 0; cb < 8; ++cb)
#pragma unroll
        for (int s = 0; s < 4; ++s) {
            short4v pk;
#pragma unroll
            for (int r = 0; r < 4; ++r) pk[r] = (short)f2bf(acc[cb][4 * s + r]);
            *(short4v*)(pb + (size_t)m * 256 + cb * 32 + 8 * s + 4 * hi) = pk;
        }
}

// ------- reduce partials + diff, in place: dh[b][m][c] = bf16( xst - (p0+p1)/(1e-9+cs) )
__global__ __launch_bounds__(256) void reduce_diff(const unsigned short* __restrict__ pxr,
                                                   const float* __restrict__ pcs,
                                                   unsigned short* __restrict__ dh) {
    size_t i = (size_t)blockIdx.x * 256 + threadIdx.x;   // over B*N*C/8
    size_t e0 = i * 8;
    int m = (int)((e0 >> 8) & (N_ - 1));
    int b = (int)(e0 >> 20);
    float cs = pcs[(size_t)b * N_ + m] + pcs[((size_t)B_ + b) * N_ + m];
    float inv = 1.f / (1e-9f + cs);
    short8v p0 = *(const short8v*)(pxr + e0);
    short8v p1 = *(const short8v*)(pxr + (size_t)B_ * N_ * 256 + e0);
    short8v xv = *(const short8v*)(dh + e0);
    short8v o;
#pragma unroll
    for (int j = 0; j < 8; ++j) {
        float xr = (bf2f((unsigned short)p0[j]) + bf2f((unsigned short)p1[j])) * inv;
        o[j] = (short)f2bf(bf2f((unsigned short)xv[j]) - xr);
    }
    *(short8v*)(dh + e0) = o;
}

// ------- t-conv + finalize (MFMA), 128-wide c-tile: out = xs + leaky(bn(t))
__global__ __launch_bounds__(512, 2) void convt_kernel(const unsigned short* __restrict__ dh,
                                                       const unsigned short* __restrict__ wh,
                                                       const float* __restrict__ bt,
                                                       const float* __restrict__ xs,
                                                       float* __restrict__ out,
                                                       const float* __restrict__ gam,
                                                       const float* __restrict__ bet,
                                                       const float* __restrict__ mu,
                                                       const float* __restrict__ var) {
    const int tid = threadIdx.x, wave = tid >> 6, lane = tid & 63, q = lane & 15, g = lane >> 4;
    const int m0 = blockIdx.x * 64, c0 = blockIdx.y * 128, b = blockIdx.z;
    const int cc = c0 + wave * 16;
    const unsigned short* db = dh + (size_t)b * N_ * 256;
    f32x4 acc[4];
#pragma unroll
    for (int j = 0; j < 4; ++j) acc[j] = (f32x4){0.f, 0.f, 0.f, 0.f};
    for (int ks = 0; ks < 8; ++ks) {
        short8v bw = *(const short8v*)(wh + (size_t)(cc + q) * 256 + ks * 32 + 8 * g);
#pragma unroll
        for (int j = 0; j < 4; ++j) {
            short8v ad = *(const short8v*)(db + (size_t)(m0 + j * 16 + q) * 256 + ks * 32 + 8 * g);
            acc[j] = __builtin_amdgcn_mfma_f32_16x16x32_bf16(ad, bw, acc[j], 0, 0, 0);
        }
    }
    const int c = cc + q;
    const float sc = rsqrtf(var[c] + 1e-5f) * gam[c];
    const float sh = bet[c] - mu[c] * sc;
    const float bb = bt[c];
#pragma unroll
    for (int j = 0; j < 4; ++j) {
        size_t off = ((size_t)b * C_ + c) * N_ + m0 + j * 16 + 4 * g;
        float4 xv = *(const float4*)(xs + off);
        float4 o;
        float tn;
        tn = (acc[j][0] + bb) * sc + sh; o.x = xv.x + (tn >= 0.f ? tn : 0.2f * tn);
        tn = (acc[j][1] + bb) * sc + sh; o.y = xv.y + (tn >= 0.f ? tn : 0.2f * tn);
        tn = (acc[j][2] + bb) * sc + sh; o.z = xv.z + (tn >= 0.f ? tn : 0.2f * tn);
        tn = (acc[j][3] + bb) * sc + sh; o.w = xv.w + (tn >= 0.f ? tn : 0.2f * tn);
        *(float4*)(out + off) = o;
    }
}

// ----------------------------------------------------------------------------------------
extern "C" void kernel_launch(void* const* d_in, const int* in_sizes, int n_in,
                              void* d_out, int out_size, void* d_ws, size_t ws_size,
                              hipStream_t stream) {
    (void)in_sizes; (void)n_in; (void)out_size; (void)ws_size;
    const float* x   = (const float*)d_in[0];
    const float* xyz = (const float*)d_in[1];
    const float* wqk = (const float*)d_in[2];
    const float* bqk = (const float*)d_in[3];
    const float* wv  = (const float*)d_in[4];
    const float* bv  = (const float*)d_in[5];
    const float* wt  = (const float*)d_in[6];
    const float* bt  = (const float*)d_in[7];
    const float* gam = (const float*)d_in[8];
    const float* bet = (const float*)d_in[9];
    const float* mu  = (const float*)d_in[10];
    const float* var = (const float*)d_in[11];
    float* out = (float*)d_out;

    const size_t M8 = (size_t)B_ * C_ * N_;   // 8M elements
    float* ws = (float*)d_ws;
    size_t off = 0;
    float* xs = ws + off;                              off += M8;       // fp32 [b][c][n] 32MB
    unsigned short* xst = (unsigned short*)(ws + off); off += M8 / 2;   // bf16 [b][n][c] 16MB
    unsigned short* Qt  = (unsigned short*)(ws + off); off += M8 / 8;   // bf16 [b][n][64] 4MB
    unsigned short* Vh  = (unsigned short*)(ws + off); off += M8 / 2;   // bf16 [b][c][n] 16MB
    unsigned short* wh  = (unsigned short*)(ws + off); off += 81920;    // bf16 weights
    float* pmax = ws + off; off += (size_t)JS_ * B_ * N_;
    float* psum = ws + off; off += (size_t)JS_ * B_ * N_;
    float* rmb  = ws + off; off += (size_t)B_ * N_;     // NEGATED row max
    float* rsb  = ws + off; off += (size_t)B_ * N_;
    float* pcs  = ws + off; off += (size_t)NSPLIT * B_ * N_;
    unsigned short* pxr = (unsigned short*)(ws + off); off += M8;       // bf16 [2][b][m][c] 32MB
    unsigned short* dhb = xst;   // reduce_diff updates xst in place -> dh

    wcvt_kernel<<<dim3(144), dim3(256), 0, stream>>>(wqk, wv, wt, wh);
    addt_kernel<<<dim3(N_ / 64, C_ / 64, B_), dim3(256), 0, stream>>>(x, xyz, xs, xst);
    convq_kernel<<<dim3(N_ / 64, B_), dim3(256), 0, stream>>>(xst, wh, bqk, Qt);
    rowstats_mfma<<<dim3(B_ * (N_ / 64) * JS_), dim3(256), 0, stream>>>(Qt, pmax, psum);
    rowmerge_kernel<<<dim3(B_ * N_ / 256), dim3(256), 0, stream>>>(pmax, psum, rmb, rsb);
    convv_kernel<<<dim3(N_ / 64, C_ / 128, B_), dim3(512), 0, stream>>>(
        xst, wh + 16384, bv, rsb, Vh);
    pv_mfma32<<<dim3(B_ * 32 * NSPLIT), dim3(256), 0, stream>>>(Qt, Vh, rmb, rsb, pxr, pcs);
    reduce_diff<<<dim3(B_ * N_ * C_ / 8 / 256), dim3(256), 0, stream>>>(pxr, pcs, dhb);
    convt_kernel<<<dim3(N_ / 64, C_ / 128, B_), dim3(512), 0, stream>>>(
        dhb, wh + 81920, bt, xs, out, gam, bet, mu, var);
}

// Round 9
// 301.879 us; speedup vs baseline: 2.1839x; 1.8817x over previous
//
#include <hip/hip_runtime.h>
#include <math.h>

#define B_   8
#define C_   256
#define N_   4096
#define CQK_ 64
#define JS_  8
#define NSPLIT 2
#define NRANGE (N_ / NSPLIT)   // 2048

// Qf is pre-scaled by sqrt(log2(e)) so q.k logits are in log2 domain: exp -> v_exp_f32.
#define SCQ 1.20110674f
#define THR2 11.54f            // defer-max threshold (8 nats in log2 units)

typedef __attribute__((ext_vector_type(8))) short short8v;    // 8 x bf16 (4 VGPRs)
typedef __attribute__((ext_vector_type(4))) short short4v;    // 4 x bf16 (8B)
typedef __attribute__((ext_vector_type(4))) float f32x4;
typedef __attribute__((ext_vector_type(16))) float f32x16;
typedef __attribute__((ext_vector_type(4))) unsigned int uint4v;

__device__ __forceinline__ unsigned short f2bf(float f) {
    unsigned u = __float_as_uint(f);
    u += 0x7fffu + ((u >> 16) & 1u);
    return (unsigned short)(u >> 16);
}
__device__ __forceinline__ float bf2f(unsigned short h) {
    return __uint_as_float((unsigned)h << 16);
}

// Fragment-major layouts (one wave load = contiguous 1KB):
//  Qf[b][nt(32n)][ks(16c)][lane][8]: element (n = nt*32 + (lane&31), c = ks*16 + (lane>>5)*8 + j)
//  Vf[b][nt16(16n)][cb(32c)][lane][8]: element (c = cb*32 + (lane&31), n = nt16*16 + (lane>>5)*8 + j)

// ------------------------------------------------ weights fp32 -> bf16 (row-major, packed)
__global__ __launch_bounds__(256) void wcvt_kernel(const float* __restrict__ wqk,
                                                   const float* __restrict__ wv,
                                                   const float* __restrict__ wt,
                                                   unsigned short* __restrict__ wh) {
    int i = (blockIdx.x * 256 + threadIdx.x) * 4;   // 144*256*4 = 147456 total
    const float* src; int off;
    if (i < 16384)      { src = wqk; off = i; }
    else if (i < 81920) { src = wv;  off = i - 16384; }
    else                { src = wt;  off = i - 81920; }
    float4 v = *(const float4*)(src + off);
    short4v o;
    o[0] = (short)f2bf(v.x); o[1] = (short)f2bf(v.y);
    o[2] = (short)f2bf(v.z); o[3] = (short)f2bf(v.w);
    *(short4v*)(wh + i) = o;
}

// --------------------------- xs = x + xyz (fp32 [b][c][n]) AND xst bf16 transposed [b][n][c]
__global__ __launch_bounds__(256) void addt_kernel(const float* __restrict__ x,
                                                   const float* __restrict__ xyz,
                                                   float* __restrict__ xs,
                                                   unsigned short* __restrict__ xst) {
    __shared__ float st[64][65];
    const int tid = threadIdx.x;
    const int n0 = blockIdx.x * 64, c0 = blockIdx.y * 64, b = blockIdx.z;
    const size_t base = ((size_t)b * C_ + c0) * N_ + n0;
#pragma unroll
    for (int r = 0; r < 4; ++r) {
        int c = r * 16 + (tid >> 4);
        int nc = (tid & 15) * 4;
        size_t off = base + (size_t)c * N_ + nc;
        float4 xv = *(const float4*)(x + off);
        float4 yv = *(const float4*)(xyz + off);
        float4 s = make_float4(xv.x + yv.x, xv.y + yv.y, xv.z + yv.z, xv.w + yv.w);
        *(float4*)(xs + off) = s;
        st[c][nc] = s.x; st[c][nc + 1] = s.y; st[c][nc + 2] = s.z; st[c][nc + 3] = s.w;
    }
    __syncthreads();
    int n = tid >> 2, cc = (tid & 3) * 16;
    short8v p0, p1;
#pragma unroll
    for (int j = 0; j < 8; ++j) {
        p0[j] = (short)f2bf(st[cc + j][n]);
        p1[j] = (short)f2bf(st[cc + 8 + j][n]);
    }
    size_t ob = ((size_t)b * N_ + n0 + n) * 256 + c0 + cc;
    *(short8v*)(xst + ob) = p0;
    *(short8v*)(xst + ob + 8) = p1;
}

// --------------------- Q-conv (MFMA): out Qf fragment-major, pre-scaled by SCQ (log2 domain)
__global__ __launch_bounds__(256, 4) void convq_kernel(const unsigned short* __restrict__ xst,
                                                       const unsigned short* __restrict__ wh,
                                                       const float* __restrict__ bias,
                                                       unsigned short* __restrict__ Qf) {
    const int tid = threadIdx.x, wave = tid >> 6, lane = tid & 63, q = lane & 15, g = lane >> 4;
    const int n0 = blockIdx.x * 64, b = blockIdx.y;
    const unsigned short* xb = xst + (size_t)b * N_ * 256;
    f32x4 acc[4];
#pragma unroll
    for (int j = 0; j < 4; ++j) acc[j] = (f32x4){0.f, 0.f, 0.f, 0.f};
    for (int ks = 0; ks < 8; ++ks) {
        short8v aw = *(const short8v*)(wh + (size_t)(wave * 16 + q) * 256 + ks * 32 + 8 * g);
#pragma unroll
        for (int j = 0; j < 4; ++j) {
            short8v bx = *(const short8v*)(xb + (size_t)(n0 + j * 16 + q) * 256 + ks * 32 + 8 * g);
            acc[j] = __builtin_amdgcn_mfma_f32_16x16x32_bf16(aw, bx, acc[j], 0, 0, 0);
        }
    }
    // element (n = n0+j*16+q, c = wave*16+4g+r) -> Qf[(b*128+nt)*4+ks=wave][hi=g>>1][l31][jj=4(g&1)+r]
#pragma unroll
    for (int j = 0; j < 4; ++j) {
        short4v pk;
#pragma unroll
        for (int r = 0; r < 4; ++r)
            pk[r] = (short)f2bf((acc[j][r] + bias[wave * 16 + 4 * g + r]) * SCQ);
        const int n = n0 + j * 16 + q;
        size_t a = ((((size_t)b * 128 + (n >> 5)) * 4 + wave) * 64 + (g >> 1) * 32 + (n & 31)) * 8
                   + (g & 1) * 4;
        *(short4v*)(Qf + a) = pk;
    }
}

// --------------------- V-conv (MFMA): out Vf fragment-major, PRE-SCALED by rsinv[n]
__global__ __launch_bounds__(512, 2) void convv_kernel(const unsigned short* __restrict__ xst,
                                                       const unsigned short* __restrict__ wh,
                                                       const float* __restrict__ bias,
                                                       const float* __restrict__ rsinv,
                                                       unsigned short* __restrict__ Vf) {
    const int tid = threadIdx.x, wave = tid >> 6, lane = tid & 63, q = lane & 15, g = lane >> 4;
    const int n0 = blockIdx.x * 64, o0 = blockIdx.y * 128, b = blockIdx.z;
    const int oo = o0 + wave * 16;
    const unsigned short* xb = xst + (size_t)b * N_ * 256;
    const float* rsb = rsinv + (size_t)b * N_;
    f32x4 acc[4];
#pragma unroll
    for (int j = 0; j < 4; ++j) acc[j] = (f32x4){0.f, 0.f, 0.f, 0.f};
    for (int ks = 0; ks < 8; ++ks) {
        short8v bw = *(const short8v*)(wh + (size_t)(oo + q) * 256 + ks * 32 + 8 * g);
#pragma unroll
        for (int j = 0; j < 4; ++j) {
            short8v ax = *(const short8v*)(xb + (size_t)(n0 + j * 16 + q) * 256 + ks * 32 + 8 * g);
            acc[j] = __builtin_amdgcn_mfma_f32_16x16x32_bf16(ax, bw, acc[j], 0, 0, 0);
        }
    }
    float bo = bias[oo + q];
    const int c = oo + q;
    // element (c, n = n0+j*16+4g+r) -> Vf[(b*256 + n0/16 + j)*8 + c>>5][hi=g>>1][c&31][4(g&1)+r]
#pragma unroll
    for (int j = 0; j < 4; ++j) {
        f32x4 rs4 = *(const f32x4*)(rsb + n0 + j * 16 + 4 * g);
        short4v pk;
#pragma unroll
        for (int r = 0; r < 4; ++r) pk[r] = (short)f2bf((acc[j][r] + bo) * rs4[r]);
        size_t a = ((((size_t)b * 256 + (n0 >> 4) + j) * 8 + (c >> 5)) * 64
                    + (g >> 1) * 32 + (c & 31)) * 8 + (g & 1) * 4;
        *(short4v*)(Vf + a) = pk;
    }
}

// ------------------ pass A: row softmax stats via 32x32 MFMA on Qf, log2 domain, defer-max
__global__ __launch_bounds__(256) void rowstats_mfma(const unsigned short* __restrict__ Qf,
                                                     float* __restrict__ pmax,
                                                     float* __restrict__ psum) {
    const int tid = threadIdx.x;
    const int wave = tid >> 6, lane = tid & 63, l31 = lane & 31;
    const int bid = blockIdx.x;
    const int b  = bid & 7;
    const int it = (bid >> 3) & 31;
    const int js = bid >> 8;
    const int i0 = it * 128 + wave * 32;
    const unsigned short* Qb = Qf + (size_t)b * 128 * 4 * 512;

    short8v bqi[4];   // B-frags: cols i (this wave's stat rows)
#pragma unroll
    for (int ks = 0; ks < 4; ++ks)
        bqi[ks] = *(const short8v*)(Qb + (((size_t)(i0 >> 5) * 4 + ks) * 64 + lane) * 8);

    float m = -1e30f, s = 0.f;
    const int jbeg = js * (N_ / JS_);
    for (int j0 = jbeg; j0 < jbeg + N_ / JS_; j0 += 32) {
        short8v an[4];
#pragma unroll
        for (int ks = 0; ks < 4; ++ks)
            an[ks] = *(const short8v*)(Qb + (((size_t)(j0 >> 5) * 4 + ks) * 64 + lane) * 8);
        f32x16 e;
#pragma unroll
        for (int r = 0; r < 16; ++r) e[r] = 0.f;
#pragma unroll
        for (int ks = 0; ks < 4; ++ks)
            e = __builtin_amdgcn_mfma_f32_32x32x16_bf16(an[ks], bqi[ks], e, 0, 0, 0);
        float pm = e[0];
#pragma unroll
        for (int r = 1; r < 16; ++r) pm = fmaxf(pm, e[r]);
        if (!__all(pm <= m + THR2)) {   // defer-max: rescale only on violation (rare)
            float mn = fmaxf(m, pm);
            s *= exp2f(m - mn);
            m = mn;
        }
#pragma unroll
        for (int r = 0; r < 16; ++r) s += exp2f(e[r] - m);
    }
    // merge hi/lo halves (each holds complementary j-subsets of column i = l31)
    {
        float mo = __shfl_xor(m, 32);
        float so = __shfl_xor(s, 32);
        float mn = fmaxf(m, mo);
        s = s * exp2f(m - mn) + so * exp2f(mo - mn);
        m = mn;
    }
    if (lane < 32) {
        size_t o = ((size_t)js * B_ + b) * N_ + i0 + l31;
        pmax[o] = m;
        psum[o] = s;
    }
}

// rowmerge: stores NEGATED rm (pv uses it directly as the MFMA C-init) + rsinv
__global__ __launch_bounds__(256) void rowmerge_kernel(const float* __restrict__ pmax,
                                                       const float* __restrict__ psum,
                                                       float* __restrict__ rmneg,
                                                       float* __restrict__ rsinv) {
    size_t i = (size_t)blockIdx.x * 256 + threadIdx.x;
    float m = -1e30f;
#pragma unroll
    for (int js = 0; js < JS_; ++js) m = fmaxf(m, pmax[(size_t)js * B_ * N_ + i]);
    float s = 0.f;
#pragma unroll
    for (int js = 0; js < JS_; ++js)
        s += psum[(size_t)js * B_ * N_ + i] * exp2f(pmax[(size_t)js * B_ * N_ + i] - m);
    rmneg[i] = -m;
    rsinv[i] = 1.f / s;
}

// --------- pass B: barrier-free, LDS-free, fragment-major operands (all loads contiguous 1KB).
// energy 32x32x16 (C-init = -rm) -> exp2 -> cvt_pk -> permlane32_swap -> PV 32x32x16.
__global__ __launch_bounds__(256, 2) void pv_mfma32(const unsigned short* __restrict__ Qf,
                                                    const unsigned short* __restrict__ Vf,
                                                    const float* __restrict__ rmneg,
                                                    const float* __restrict__ rsinv,
                                                    unsigned short* __restrict__ pxr,
                                                    float* __restrict__ pcs) {
    const int tid = threadIdx.x;
    const int wave = tid >> 6, lane = tid & 63, l31 = lane & 31, hi = lane >> 5;
    const int bid = blockIdx.x;
    const int b  = bid & 7;                 // XCD-pinned: one batch per XCD
    const int mc = (bid >> 3) & 31;
    const int ns = bid >> 8;
    const int m0 = mc * 128 + wave * 32;    // this wave's m-tile
    const int nbeg = ns * NRANGE;
    const unsigned short* Qb = Qf + (size_t)b * 128 * 4 * 512;
    const unsigned short* Vb = Vf + (size_t)b * 256 * 8 * 512;
    const float* rmb = rmneg + (size_t)b * N_;
    const float* rsb = rsinv + (size_t)b * N_;

    // persistent energy B-frags: cols m = m0+l31
    short8v bqm[4];
#pragma unroll
    for (int ks = 0; ks < 4; ++ks)
        bqm[ks] = *(const short8v*)(Qb + (((size_t)(m0 >> 5) * 4 + ks) * 64 + lane) * 8);

    f32x16 acc[8];
#pragma unroll
    for (int cb = 0; cb < 8; ++cb)
#pragma unroll
        for (int r = 0; r < 16; ++r) acc[cb][r] = 0.f;
    f32x4 csum4 = {0.f, 0.f, 0.f, 0.f};

#pragma unroll 1
    for (int it = 0; it < NRANGE / 32; ++it) {
        const int n0 = nbeg + it * 32;
        const int nt = n0 >> 5;
        // A-frags (rows n) — contiguous 1KB each
        short8v an[4];
#pragma unroll
        for (int ks = 0; ks < 4; ++ks)
            an[ks] = *(const short8v*)(Qb + (((size_t)nt * 4 + ks) * 64 + lane) * 8);
        // stats (broadcast loads, L2-hot): reg r+4s -> n = n0 + 8s + 4hi + r
        f32x4 rmn[4], rs[4];
#pragma unroll
        for (int s = 0; s < 4; ++s) {
            rmn[s] = *(const f32x4*)(rmb + n0 + 8 * s + 4 * hi);
            rs[s]  = *(const f32x4*)(rsb + n0 + 8 * s + 4 * hi);
        }
        // energy: C-init = -rm (free subtraction), 4 chained k-steps
        f32x16 e;
#pragma unroll
        for (int s = 0; s < 4; ++s) {
            e[4 * s + 0] = rmn[s][0]; e[4 * s + 1] = rmn[s][1];
            e[4 * s + 2] = rmn[s][2]; e[4 * s + 3] = rmn[s][3];
        }
#pragma unroll
        for (int ks = 0; ks < 4; ++ks)
            e = __builtin_amdgcn_mfma_f32_32x32x16_bf16(an[ks], bqm[ks], e, 0, 0, 0);
        // exp2 + csum + pack to bf16 dword pairs
        unsigned dw[8];
#pragma unroll
        for (int s = 0; s < 4; ++s) {
            float p0 = exp2f(e[4 * s + 0]);
            float p1 = exp2f(e[4 * s + 1]);
            float p2 = exp2f(e[4 * s + 2]);
            float p3 = exp2f(e[4 * s + 3]);
            csum4[s] += (p0 * rs[s][0] + p1 * rs[s][1]) + (p2 * rs[s][2] + p3 * rs[s][3]);
            asm("v_cvt_pk_bf16_f32 %0, %1, %2" : "=v"(dw[2 * s + 0]) : "v"(p0), "v"(p1));
            asm("v_cvt_pk_bf16_f32 %0, %1, %2" : "=v"(dw[2 * s + 1]) : "v"(p2), "v"(p3));
        }
        // lane-half exchange: a' = [a_lo|b_lo], b' = [a_hi|b_hi]  (exact B-frag words)
        asm("v_permlane32_swap_b32 %0, %1" : "+v"(dw[0]), "+v"(dw[2]));
        asm("v_permlane32_swap_b32 %0, %1" : "+v"(dw[1]), "+v"(dw[3]));
        asm("v_permlane32_swap_b32 %0, %1" : "+v"(dw[4]), "+v"(dw[6]));
        asm("v_permlane32_swap_b32 %0, %1" : "+v"(dw[5]), "+v"(dw[7]));
        uint4v t0 = {dw[0], dw[1], dw[2], dw[3]};
        uint4v t1 = {dw[4], dw[5], dw[6], dw[7]};
        short8v pf0 = __builtin_bit_cast(short8v, t0);   // P rows n0..n0+15
        short8v pf1 = __builtin_bit_cast(short8v, t1);   // P rows n0+16..n0+31
        // PV: acc[c][m] += V'[c][n] * P[n][m]; Vf loads contiguous 1KB
        const size_t vb0 = (size_t)(nt * 2) * 8;
#pragma unroll
        for (int cb = 0; cb < 8; ++cb) {
            short8v v0 = *(const short8v*)(Vb + ((vb0 + cb) * 64 + lane) * 8);
            acc[cb] = __builtin_amdgcn_mfma_f32_32x32x16_bf16(v0, pf0, acc[cb], 0, 0, 0);
        }
#pragma unroll
        for (int cb = 0; cb < 8; ++cb) {
            short8v v1 = *(const short8v*)(Vb + ((vb0 + 8 + cb) * 64 + lane) * 8);
            acc[cb] = __builtin_amdgcn_mfma_f32_32x32x16_bf16(v1, pf1, acc[cb], 0, 0, 0);
        }
    }

    // partial colsum: lanes l and l+32 hold complementary n-halves of column m
    float csum = (csum4[0] + csum4[1]) + (csum4[2] + csum4[3]);
    csum += __shfl_xor(csum, 32);
    if (lane < 32) pcs[((size_t)ns * B_ + b) * N_ + m0 + lane] = csum;
    // partial XR out: bf16 [ns][b][m][c]; c = cb*32 + 8s + 4hi + r
    unsigned short* pb = pxr + ((size_t)ns * B_ + b) * N_ * 256;
    const int m = m0 + l31;
#pragma unroll
    for (int cb = 0; cb < 8; ++cb)
#pragma unroll
        for (int s = 0; s < 4; ++s) {
            short4v pk;
#pragma unroll
            for (int r = 0; r < 4; ++r) pk[r] = (short)f2bf(acc[cb][4 * s + r]);
            *(short4v*)(pb + (size_t)m * 256 + cb * 32 + 8 * s + 4 * hi) = pk;
        }
}

// ------- reduce partials + diff, in place: dh[b][m][c] = bf16( xst - (p0+p1)/(1e-9+cs) )
__global__ __launch_bounds__(256) void reduce_diff(const unsigned short* __restrict__ pxr,
                                                   const float* __restrict__ pcs,
                                                   unsigned short* __restrict__ dh) {
    size_t i = (size_t)blockIdx.x * 256 + threadIdx.x;   // over B*N*C/8
    size_t e0 = i * 8;
    int m = (int)((e0 >> 8) & (N_ - 1));
    int b = (int)(e0 >> 20);
    float cs = pcs[(size_t)b * N_ + m] + pcs[((size_t)B_ + b) * N_ + m];
    float inv = 1.f / (1e-9f + cs);
    short8v p0 = *(const short8v*)(pxr + e0);
    short8v p1 = *(const short8v*)(pxr + (size_t)B_ * N_ * 256 + e0);
    short8v xv = *(const short8v*)(dh + e0);
    short8v o;
#pragma unroll
    for (int j = 0; j < 8; ++j) {
        float xr = (bf2f((unsigned short)p0[j]) + bf2f((unsigned short)p1[j])) * inv;
        o[j] = (short)f2bf(bf2f((unsigned short)xv[j]) - xr);
    }
    *(short8v*)(dh + e0) = o;
}

// ------- t-conv + finalize (MFMA), 128-wide c-tile: out = xs + leaky(bn(t))
__global__ __launch_bounds__(512, 2) void convt_kernel(const unsigned short* __restrict__ dh,
                                                       const unsigned short* __restrict__ wh,
                                                       const float* __restrict__ bt,
                                                       const float* __restrict__ xs,
                                                       float* __restrict__ out,
                                                       const float* __restrict__ gam,
                                                       const float* __restrict__ bet,
                                                       const float* __restrict__ mu,
                                                       const float* __restrict__ var) {
    const int tid = threadIdx.x, wave = tid >> 6, lane = tid & 63, q = lane & 15, g = lane >> 4;
    const int m0 = blockIdx.x * 64, c0 = blockIdx.y * 128, b = blockIdx.z;
    const int cc = c0 + wave * 16;
    const unsigned short* db = dh + (size_t)b * N_ * 256;
    f32x4 acc[4];
#pragma unroll
    for (int j = 0; j < 4; ++j) acc[j] = (f32x4){0.f, 0.f, 0.f, 0.f};
    for (int ks = 0; ks < 8; ++ks) {
        short8v bw = *(const short8v*)(wh + (size_t)(cc + q) * 256 + ks * 32 + 8 * g);
#pragma unroll
        for (int j = 0; j < 4; ++j) {
            short8v ad = *(const short8v*)(db + (size_t)(m0 + j * 16 + q) * 256 + ks * 32 + 8 * g);
            acc[j] = __builtin_amdgcn_mfma_f32_16x16x32_bf16(ad, bw, acc[j], 0, 0, 0);
        }
    }
    const int c = cc + q;
    const float sc = rsqrtf(var[c] + 1e-5f) * gam[c];
    const float sh = bet[c] - mu[c] * sc;
    const float bb = bt[c];
#pragma unroll
    for (int j = 0; j < 4; ++j) {
        size_t off = ((size_t)b * C_ + c) * N_ + m0 + j * 16 + 4 * g;
        float4 xv = *(const float4*)(xs + off);
        float4 o;
        float tn;
        tn = (acc[j][0] + bb) * sc + sh; o.x = xv.x + (tn >= 0.f ? tn : 0.2f * tn);
        tn = (acc[j][1] + bb) * sc + sh; o.y = xv.y + (tn >= 0.f ? tn : 0.2f * tn);
        tn = (acc[j][2] + bb) * sc + sh; o.z = xv.z + (tn >= 0.f ? tn : 0.2f * tn);
        tn = (acc[j][3] + bb) * sc + sh; o.w = xv.w + (tn >= 0.f ? tn : 0.2f * tn);
        *(float4*)(out + off) = o;
    }
}

// ----------------------------------------------------------------------------------------
extern "C" void kernel_launch(void* const* d_in, const int* in_sizes, int n_in,
                              void* d_out, int out_size, void* d_ws, size_t ws_size,
                              hipStream_t stream) {
    (void)in_sizes; (void)n_in; (void)out_size; (void)ws_size;
    const float* x   = (const float*)d_in[0];
    const float* xyz = (const float*)d_in[1];
    const float* wqk = (const float*)d_in[2];
    const float* bqk = (const float*)d_in[3];
    const float* wv  = (const float*)d_in[4];
    const float* bv  = (const float*)d_in[5];
    const float* wt  = (const float*)d_in[6];
    const float* bt  = (const float*)d_in[7];
    const float* gam = (const float*)d_in[8];
    const float* bet = (const float*)d_in[9];
    const float* mu  = (const float*)d_in[10];
    const float* var = (const float*)d_in[11];
    float* out = (float*)d_out;

    const size_t M8 = (size_t)B_ * C_ * N_;   // 8M elements
    float* ws = (float*)d_ws;
    size_t off = 0;
    float* xs = ws + off;                              off += M8;       // fp32 [b][c][n] 32MB
    unsigned short* xst = (unsigned short*)(ws + off); off += M8 / 2;   // bf16 [b][n][c] 16MB
    unsigned short* Qf  = (unsigned short*)(ws + off); off += M8 / 8;   // bf16 frag-major 4MB
    unsigned short* Vf  = (unsigned short*)(ws + off); off += M8 / 2;   // bf16 frag-major 16MB
    unsigned short* wh  = (unsigned short*)(ws + off); off += 81920;    // bf16 weights
    float* pmax = ws + off; off += (size_t)JS_ * B_ * N_;
    float* psum = ws + off; off += (size_t)JS_ * B_ * N_;
    float* rmb  = ws + off; off += (size_t)B_ * N_;     // NEGATED row max
    float* rsb  = ws + off; off += (size_t)B_ * N_;
    float* pcs  = ws + off; off += (size_t)NSPLIT * B_ * N_;
    unsigned short* pxr = (unsigned short*)(ws + off); off += M8;       // bf16 [2][b][m][c] 32MB
    unsigned short* dhb = xst;   // reduce_diff updates xst in place -> dh

    wcvt_kernel<<<dim3(144), dim3(256), 0, stream>>>(wqk, wv, wt, wh);
    addt_kernel<<<dim3(N_ / 64, C_ / 64, B_), dim3(256), 0, stream>>>(x, xyz, xs, xst);
    convq_kernel<<<dim3(N_ / 64, B_), dim3(256), 0, stream>>>(xst, wh, bqk, Qf);
    rowstats_mfma<<<dim3(B_ * 32 * JS_), dim3(256), 0, stream>>>(Qf, pmax, psum);
    rowmerge_kernel<<<dim3(B_ * N_ / 256), dim3(256), 0, stream>>>(pmax, psum, rmb, rsb);
    convv_kernel<<<dim3(N_ / 64, C_ / 128, B_), dim3(512), 0, stream>>>(
        xst, wh + 16384, bv, rsb, Vf);
    pv_mfma32<<<dim3(B_ * 32 * NSPLIT), dim3(256), 0, stream>>>(Qf, Vf, rmb, rsb, pxr, pcs);
    reduce_diff<<<dim3(B_ * N_ * C_ / 8 / 256), dim3(256), 0, stream>>>(pxr, pcs, dhb);
    convt_kernel<<<dim3(N_ / 64, C_ / 128, B_), dim3(512), 0, stream>>>(
        dhb, wh + 81920, bt, xs, out, gam, bet, mu, var);
}